// Round 7
// baseline (517.137 us; speedup 1.0000x reference)
//
#include <hip/hip_runtime.h>
#include <cstdint>

using u16 = unsigned short;
using u32 = unsigned int;
typedef __attribute__((ext_vector_type(8))) short short8;
typedef __attribute__((ext_vector_type(4))) float f32x4;
typedef __attribute__((ext_vector_type(16))) float f32x16;

__device__ __forceinline__ float bf2f(u16 u) { return __uint_as_float(((u32)u) << 16); }
__device__ __forceinline__ u16 f2bf(float f) {
    u32 u = __float_as_uint(f);
    u32 r = u + 0x7fffu + ((u >> 16) & 1u);   // round-to-nearest-even
    return (u16)(r >> 16);
}

__device__ __forceinline__ void load_lds16(const void* g, void* l) {
    __builtin_amdgcn_global_load_lds((const __attribute__((address_space(1))) void*)g,
                                     (__attribute__((address_space(3))) void*)l, 16, 0, 0);
}

// ---------------- LayerNorm row body (1024 fp32 -> bf16) ----------------
__device__ __forceinline__ void ln_row(const float* __restrict__ x,
                                       const float* __restrict__ gw,
                                       const float* __restrict__ bw,
                                       u16* __restrict__ y, int row) {
    const int tid = threadIdx.x;
    const float4 v = ((const float4*)(x + (size_t)row * 1024))[tid];
    float s  = v.x + v.y + v.z + v.w;
    float ss = v.x * v.x + v.y * v.y + v.z * v.z + v.w * v.w;
#pragma unroll
    for (int off = 32; off; off >>= 1) {
        s  += __shfl_xor(s, off);
        ss += __shfl_xor(ss, off);
    }
    __shared__ float sm[8];
    const int lane = tid & 63, wid = tid >> 6;
    if (lane == 0) { sm[wid] = s; sm[wid + 4] = ss; }
    __syncthreads();
    s  = sm[0] + sm[1] + sm[2] + sm[3];
    ss = sm[4] + sm[5] + sm[6] + sm[7];
    const float mu   = s * (1.0f / 1024.0f);
    const float var  = ss * (1.0f / 1024.0f) - mu * mu;
    const float rstd = rsqrtf(var + 1e-5f);
    const float4 g4 = ((const float4*)gw)[tid];
    const float4 b4 = ((const float4*)bw)[tid];
    u16 o[4];
    o[0] = f2bf((v.x - mu) * rstd * g4.x + b4.x);
    o[1] = f2bf((v.y - mu) * rstd * g4.y + b4.y);
    o[2] = f2bf((v.z - mu) * rstd * g4.z + b4.z);
    o[3] = f2bf((v.w - mu) * rstd * g4.w + b4.w);
    *(uint2*)(y + (size_t)row * 1024 + tid * 4) = *(uint2*)o;
}

__global__ __launch_bounds__(256)
void ln_cast_kernel(const float* __restrict__ x, const float* __restrict__ gw,
                    const float* __restrict__ bw, u16* __restrict__ y) {
    ln_row(x, gw, bw, y, blockIdx.x);
}

// merged: all 3 layernorms in one dispatch (sel = bid>>14)
__global__ __launch_bounds__(256)
void ln3_kernel(const float* __restrict__ x0, const float* __restrict__ x1,
                const float* __restrict__ x2,
                const float* __restrict__ g0, const float* __restrict__ g1,
                const float* __restrict__ g2,
                const float* __restrict__ b0, const float* __restrict__ b1,
                const float* __restrict__ b2, u16* __restrict__ y) {
    const int bid = blockIdx.x;
    const int sel = bid >> 14;
    const int row = bid & 16383;
    const float* x  = (sel == 0) ? x0 : (sel == 1) ? x1 : x2;
    const float* gw = (sel == 0) ? g0 : (sel == 1) ? g1 : g2;
    const float* bw = (sel == 0) ? b0 : (sel == 1) ? b1 : b2;
    ln_row(x, gw, bw, y + ((size_t)sel << 24), row);
}

// ---------------- fp32 -> bf16 cast of the 3 weight matrices ----------------
__global__ __launch_bounds__(256)
void cast3_kernel(const float* __restrict__ wa, const float* __restrict__ wb,
                  const float* __restrict__ wc, u16* __restrict__ oa) {
    const int bid = blockIdx.x;
    const int sel = bid >> 10;
    const float* s = (sel == 0) ? wa : (sel == 1) ? wb : wc;
    u16* d = oa + (size_t)sel * 1048576;
    const int i = (bid & 1023) * 256 + threadIdx.x;
    const float4 v = ((const float4*)s)[i];
    u16 o[4] = { f2bf(v.x), f2bf(v.y), f2bf(v.z), f2bf(v.w) };
    *(uint2*)(d + (size_t)i * 4) = *(uint2*)o;
}

// ---------------- zero the softmax-denominator buffer (64 KB) -------------
__global__ __launch_bounds__(256)
void zerof_kernel(float* __restrict__ p) {
    p[blockIdx.x * 256 + threadIdx.x] = 0.0f;
}

// ---------------- old 128x128 GEMM (fallback path only) -------------------
template<int MODE>
__global__ __launch_bounds__(256, (MODE == 3 ? 3 : 4))
void gemm_bt(const u16* __restrict__ A, const u16* __restrict__ B,
             const float* __restrict__ bias0, const float* __restrict__ bias1,
             const float* __restrict__ bias2,
             void* __restrict__ Cout, void* __restrict__ Cout2,
             const int M, const int N, const int K, const float scale,
             const long sA, const long sB, const long sC)
{
    int bz, m0, n0;
    if (MODE == 2 || MODE == 3) {
        const int id = blockIdx.x;
        bz = id & 7;                      // one batch per XCD
        m0 = ((id >> 3) & 15) * 128;
        n0 = (id >> 7) * 128;
    } else {
        bz = (MODE == 4) ? blockIdx.z : 0;
        m0 = blockIdx.x * 128;
        n0 = blockIdx.y * 128;
    }
    A += (long)bz * sA;
    B += (long)bz * sB;
    const float* bias = (MODE == 4) ? (bz == 0 ? bias0 : bz == 1 ? bias1 : bias2)
                                    : bias0;
    __shared__ __align__(16) u16 As[128 * 64];
    __shared__ __align__(16) u16 Bs[128 * 64];
    const int tid  = threadIdx.x;
    const int lane = tid & 63, wid = tid >> 6;
    const int wm = (wid & 1) * 64, wn = (wid >> 1) * 64;

    const int scol = (tid & 7) ^ ((tid >> 3) & 7);
    const u16* ap = A + (long)(m0 + (tid >> 3)) * K + scol * 8;
    const u16* bp = B + (long)(n0 + (tid >> 3)) * K + scol * 8;
    u16* asd = As + wid * 512;
    u16* bsd = Bs + wid * 512;
    const long rs32 = 32L * K;

    f32x4 acc[4][4] = {};
    f32x4 acc_l[4] = {};
    const short8 ones8 = {16256, 16256, 16256, 16256, 16256, 16256, 16256, 16256};
    const int fr = lane & 15, fq = lane >> 4;
    const int sw = (fq ^ (fr & 7)) * 8;
    const int offA0 = (wm + fr) * 64 + sw;
    const int offA1 = offA0 ^ 32;
    const int offB0 = (wn + fr) * 64 + sw;
    const int offB1 = offB0 ^ 32;

    for (int k0 = 0; k0 < K; k0 += 64) {
#pragma unroll
        for (int rd = 0; rd < 4; rd++) {
            load_lds16(ap + k0 + rd * rs32, asd + rd * 2048);
            load_lds16(bp + k0 + rd * rs32, bsd + rd * 2048);
        }
        __syncthreads();
#pragma unroll
        for (int s = 0; s < 2; s++) {
            const int oa = s ? offA1 : offA0;
            const int ob = s ? offB1 : offB0;
            short8 b0 = *(const short8*)&Bs[ob];
            short8 b1 = *(const short8*)&Bs[ob + 1024];
            short8 b2 = *(const short8*)&Bs[ob + 2048];
            short8 b3 = *(const short8*)&Bs[ob + 3072];
#pragma unroll
            for (int i = 0; i < 4; i++) {
                const short8 a = *(const short8*)&As[oa + i * 1024];
                acc[i][0] = __builtin_amdgcn_mfma_f32_16x16x32_bf16(a, b0, acc[i][0], 0, 0, 0);
                acc[i][1] = __builtin_amdgcn_mfma_f32_16x16x32_bf16(a, b1, acc[i][1], 0, 0, 0);
                acc[i][2] = __builtin_amdgcn_mfma_f32_16x16x32_bf16(a, b2, acc[i][2], 0, 0, 0);
                acc[i][3] = __builtin_amdgcn_mfma_f32_16x16x32_bf16(a, b3, acc[i][3], 0, 0, 0);
                if (MODE == 3)
                    acc_l[i] = __builtin_amdgcn_mfma_f32_16x16x32_bf16(a, ones8, acc_l[i], 0, 0, 0);
            }
        }
        __syncthreads();
    }

    const int cn = lane & 15;
    const int cm = (lane >> 4) * 4;
    float invl[4][4];
    if (MODE == 3) {
#pragma unroll
        for (int i = 0; i < 4; i++)
#pragma unroll
            for (int r = 0; r < 4; r++) invl[i][r] = 1.0f / acc_l[i][r];
    }
#pragma unroll
    for (int i = 0; i < 4; i++) {
        const int gmb = m0 + wm + i * 16 + cm;
#pragma unroll
        for (int j = 0; j < 4; j++) {
            const int gn = n0 + wn + j * 16 + cn;
            const float bv = (MODE <= 1 || MODE == 4) ? bias[gn] : 0.0f;
            if (MODE == 1 || (MODE == 4 && bz == 2)) {
                u16* dst = (MODE == 4) ? (u16*)Cout2 : (u16*)Cout;
                const int batch = gmb >> 11;
                const int jj = gmb & 2047;
                u16 o[4];
#pragma unroll
                for (int r = 0; r < 4; r++) o[r] = f2bf(acc[i][j][r] + bv);
                *(uint2*)(dst + ((long)batch * N + gn) * 2048 + jj) = *(uint2*)o;
            } else if (MODE == 0 || MODE == 4) {
                u16* dst = (u16*)Cout + ((MODE == 4) ? (long)bz * 16777216 : 0);
#pragma unroll
                for (int r = 0; r < 4; r++)
                    dst[(long)(gmb + r) * N + gn] = f2bf(acc[i][j][r] + bv);
            } else {
#pragma unroll
                for (int r = 0; r < 4; r++) {
                    const long gm = gmb + r;
                    float v = acc[i][j][r];
                    if (MODE == 2) v = __expf(v * scale);
                    if (MODE == 3)
                        ((float*)Cout)[(long)bz * sC + gm * N + gn] = v * invl[i][r];
                    else
                        ((u16*)Cout)[(long)bz * sC + gm * N + gn] = f2bf(v);
                }
            }
        }
    }
}

// ============ 256x256 8-phase quadrant GEMM, 32x32x16 MFMA (r13) ==========
// r12 post-mortem: all GEMMs plateau ~33% MfmaUtil on 16x16x32. r13 swaps the
// MFMA shape: 32x32x16 runs at 2382-2495 TF ubench vs 2075 (16x16) — ~16-20%
// less matrix-pipe time, half the MFMA instruction count. Per wave: 4m x 2n
// tiles of 32x32, acc = 8 x f32x16 (128 VGPR, unchanged). Same [128][64]
// swizzled LDS halves, same quadrant phases / staging placement / vmcnt(8)
// accounting as r11/r12 (verified over 4 passing rounds).
// Fragments: A row=l&31, k=(l>>5)*8+e (k-mapping only needs A/B consistency);
// C/D (HW-verified m74/m101): col=lane&31, row=(r&3)+8*(r>>2)+4*(lane>>5).
__device__ __forceinline__ void ph_mid() {      // after reads+stage issued
    __builtin_amdgcn_sched_barrier(0);
    __builtin_amdgcn_s_barrier();
    asm volatile("s_waitcnt lgkmcnt(0)" ::: "memory");
    __builtin_amdgcn_sched_barrier(0);
}
__device__ __forceinline__ void ph_end() {      // after MFMA cluster
    __builtin_amdgcn_sched_barrier(0);
    __builtin_amdgcn_s_barrier();
    __builtin_amdgcn_sched_barrier(0);
}

// A quadrant mh: 2 m-sub-tiles x 4 k-slices (8 x ds_read_b128)
#define RDAH32(reg, mh) do { \
    aF[0] = *(const short8*)&(reg)[baseA + (mh)*8192 +        sw0]; \
    aF[1] = *(const short8*)&(reg)[baseA + (mh)*8192 +        sw1]; \
    aF[2] = *(const short8*)&(reg)[baseA + (mh)*8192 +        sw2]; \
    aF[3] = *(const short8*)&(reg)[baseA + (mh)*8192 +        sw3]; \
    aF[4] = *(const short8*)&(reg)[baseA + (mh)*8192 + 2048 + sw0]; \
    aF[5] = *(const short8*)&(reg)[baseA + (mh)*8192 + 2048 + sw1]; \
    aF[6] = *(const short8*)&(reg)[baseA + (mh)*8192 + 2048 + sw2]; \
    aF[7] = *(const short8*)&(reg)[baseA + (mh)*8192 + 2048 + sw3]; } while (0)

// B half nh: 1 n-tile x 4 k-slices (4 x ds_read_b128)
#define RDBH32(dst, reg, nh) do { \
    dst[0] = *(const short8*)&(reg)[baseB + (nh)*8192 + sw0]; \
    dst[1] = *(const short8*)&(reg)[baseB + (nh)*8192 + sw1]; \
    dst[2] = *(const short8*)&(reg)[baseB + (nh)*8192 + sw2]; \
    dst[3] = *(const short8*)&(reg)[baseB + (nh)*8192 + sw3]; } while (0)

// one C-quadrant x K=64: 8 MFMA (k-slice outer, same-acc dep distance 2;
// at 2 waves/SIMD the ~65-cyc same-wave reissue gap covers MFMA latency)
#define MMQ32(mh, jt, bF) do { \
    __builtin_amdgcn_s_setprio(1); \
    _Pragma("unroll") \
    for (int s_ = 0; s_ < 4; s_++) { \
        _Pragma("unroll") \
        for (int i_ = 0; i_ < 2; i_++) \
            acc[(mh)*2 + i_][jt] = __builtin_amdgcn_mfma_f32_32x32x16_bf16( \
                aF[i_*4 + s_], bF[s_], acc[(mh)*2 + i_][jt], 0, 0, 0); \
    } \
    __builtin_amdgcn_s_setprio(0); } while (0)

#define STA(reg, hm, kt) do { \
    const u16* s_ = apg + (hm) * rH + (long)(kt) * 64; \
    u16* d_ = (reg) + (hm) * 8192 + w * 1024; \
    load_lds16(s_, d_); \
    load_lds16(s_ + rK8, d_ + 512); } while (0)

#define STB(reg, hm, kt) do { \
    const u16* s_ = bpg + (hm) * rH + (long)(kt) * 64; \
    u16* d_ = (reg) + (hm) * 8192 + w * 1024; \
    load_lds16(s_, d_); \
    load_lds16(s_ + rK8, d_ + 512); } while (0)

// MODE 2: bf16 out = exp(acc*scale) + rowsum atomics into Cout2
// MODE 4: merged QKV, grid(M/256, N/256, 3); z<2 row-major +bias, z=2 vT
// MODE 5: fp32 out = acc / L[row]  (L via bias0)
template<int MODE>
__global__ __launch_bounds__(512, 1)
void gemm8(const u16* __restrict__ A, const u16* __restrict__ B,
           const float* __restrict__ bias0, const float* __restrict__ bias1,
           const float* __restrict__ bias2,
           void* __restrict__ Cout, void* __restrict__ Cout2,
           const int M, const int N, const int K, const float scale,
           const long sA, const long sB, const long sC)
{
    int bz, m0, n0;
    if (MODE == 2 || MODE == 5) {
        const int id = blockIdx.x;
        bz = id & 7;                      // one batch per XCD
        m0 = ((id >> 3) & 7) * 256;
        n0 = (id >> 6) * 256;
    } else {
        bz = blockIdx.z;
        m0 = blockIdx.x * 256;
        n0 = blockIdx.y * 256;
    }
    A += (long)bz * sA;
    B += (long)bz * sB;
    const float* bias = (MODE == 4) ? (bz == 0 ? bias0 : bz == 1 ? bias1 : bias2)
                                    : bias0;

    __shared__ __align__(16) u16 lds[65536];   // 128 KiB
    u16* const Ar0 = lds;
    u16* const Ar1 = lds + 16384;
    u16* const Br0 = lds + 32768;
    u16* const Br1 = lds + 49152;

    const int tid = threadIdx.x;
    const int w = tid >> 6, l = tid & 63;
    // staging: wave w covers rows w*16 + (l>>3) (+8 for 2nd load) of a
    // 128-row half; global col-group pre-swizzled so the linear LDS fill
    // realizes LDS[r*64 + ((cg ^ (r&7))*8)] = global cols cg*8.. of row r.
    const int cgrp = (l & 7) ^ ((l >> 3) & 7);
    const long rK8 = 8L * K;
    const long rH  = 128L * K;
    const u16* apg = A + (long)(m0 + w * 16 + (l >> 3)) * K + cgrp * 8;
    const u16* bpg = B + (long)(n0 + w * 16 + (l >> 3)) * K + cgrp * 8;

    const int w1 = w & 1;                 // M sub-band within a 128-row half
    const int wn2 = (w >> 1) * 32;        // N sub-band within a 128-col half
    const int hi = l >> 5;                // k-group of this lane
    const int x7 = l & 7;                 // swizzle class (row&7 for A and B)
    // per-slice swizzled col offsets (elements): ((s*2+hi) ^ (row&7)) * 8
    const int sw0 = ((0 + hi) ^ x7) << 3;
    const int sw1 = ((2 + hi) ^ x7) << 3;
    const int sw2 = ((4 + hi) ^ x7) << 3;
    const int sw3 = ((6 + hi) ^ x7) << 3;
    const int baseA = (w1 * 64 + (l & 31)) * 64;   // + mh*8192 + i*2048
    const int baseB = (wn2 + (l & 31)) * 64;       // + nh*8192

    f32x16 acc[4][2] = {};
    short8 aF[8];
    short8 bF0[4], bF1[4];

    // prologue: tile0 -> buf0, tile1 -> buf1 (B-halves then A-halves each)
    STB(Br0, 0, 0); STB(Br0, 1, 0); STA(Ar0, 0, 0); STA(Ar0, 1, 0);
    STB(Br1, 0, 1); STB(Br1, 1, 1); STA(Ar1, 0, 1); STA(Ar1, 1, 1);
    __builtin_amdgcn_sched_barrier(0);
    asm volatile("s_waitcnt vmcnt(8)" ::: "memory");   // tile0 landed
    __builtin_amdgcn_s_barrier();
    asm volatile("" ::: "memory");
    __builtin_amdgcn_sched_barrier(0);

    const int NI = K >> 7;                // 2 K-tiles per iteration
    for (int it = 0; it < NI; ++it) {
        const bool nl = (it < NI - 1);
        const int t2 = 2 * it + 2, t3 = 2 * it + 3;
        // ---- tile 2it from buf0 ----
        // P1: rd A-q0 (8) + B-h0 (4); MFMA Q00   (touches halves Ah0, Bh0)
        RDAH32(Ar0, 0); RDBH32(bF0, Br0, 0);
        ph_mid();
        MMQ32(0, 0, bF0);
        ph_end();
        // P2: rd B-h1 (4); stage Bh0(t2)+Ah0(t2); MFMA Q01
        RDBH32(bF1, Br0, 1);
        if (nl) { STB(Br0, 0, t2); STA(Ar0, 0, t2); }
        ph_mid();
        MMQ32(0, 1, bF1);
        ph_end();
        // P3: rd A-q1 (8, half Ah1); stage Bh1(t2); MFMA Q10
        RDAH32(Ar0, 1);
        if (nl) STB(Br0, 1, t2);
        ph_mid();
        MMQ32(1, 0, bF0);
        ph_end();
        // P4: stage Ah1(t2); MFMA Q11; gate vmcnt -> buf1 (odd tile) landed
        if (nl) STA(Ar0, 1, t2);
        ph_mid();
        MMQ32(1, 1, bF1);
        __builtin_amdgcn_sched_barrier(0);
        if (nl) asm volatile("s_waitcnt vmcnt(8)" ::: "memory");
        else    asm volatile("s_waitcnt vmcnt(0)" ::: "memory");
        __builtin_amdgcn_s_barrier();
        asm volatile("" ::: "memory");
        __builtin_amdgcn_sched_barrier(0);
        // ---- tile 2it+1 from buf1 ----
        // P5: rd A-q0 + B-h0; MFMA Q00
        RDAH32(Ar1, 0); RDBH32(bF0, Br1, 0);
        ph_mid();
        MMQ32(0, 0, bF0);
        ph_end();
        // P6: rd B-h1; stage Bh0(t3)+Ah0(t3); MFMA Q01
        RDBH32(bF1, Br1, 1);
        if (nl) { STB(Br1, 0, t3); STA(Ar1, 0, t3); }
        ph_mid();
        MMQ32(0, 1, bF1);
        ph_end();
        // P7: rd A-q1; stage Bh1(t3); MFMA Q10
        RDAH32(Ar1, 1);
        if (nl) STB(Br1, 1, t3);
        ph_mid();
        MMQ32(1, 0, bF0);
        ph_end();
        // P8: stage Ah1(t3); MFMA Q11; gate vmcnt -> buf0 (t2) landed
        if (nl) STA(Ar1, 1, t3);
        ph_mid();
        MMQ32(1, 1, bF1);
        __builtin_amdgcn_sched_barrier(0);
        if (nl) asm volatile("s_waitcnt vmcnt(8)" ::: "memory");
        else    asm volatile("s_waitcnt vmcnt(0)" ::: "memory");
        __builtin_amdgcn_s_barrier();
        asm volatile("" ::: "memory");
        __builtin_amdgcn_sched_barrier(0);
    }

    // epilogue: 32x32 C/D layout col=lane&31, row=(r&3)+8*(r>>2)+4*hi
    // acc[i][j]: global row = m0 + (i>>1)*128 + w1*64 + (i&1)*32 + tile-row
    //            global col = n0 + j*128 + wn2 + (l&31)
    const int cn = l & 31;
#pragma unroll
    for (int i = 0; i < 4; i++) {
        const int gb = m0 + (i >> 1) * 128 + w1 * 64 + (i & 1) * 32;
        float rs[16];
        if (MODE == 2) {
#pragma unroll
            for (int r = 0; r < 16; r++) rs[r] = 0.0f;
        }
#pragma unroll
        for (int j = 0; j < 2; j++) {
            const int gn = n0 + j * 128 + wn2 + cn;
            if (MODE == 4) {
                const float bv = bias[gn];
                if (bz == 2) {
                    const int batch = gb >> 11;
#pragma unroll
                    for (int q = 0; q < 4; q++) {
                        const int jj = (gb & 2047) + q * 8 + hi * 4;
                        u16 o[4];
#pragma unroll
                        for (int d = 0; d < 4; d++) o[d] = f2bf(acc[i][j][q*4+d] + bv);
                        *(uint2*)((u16*)Cout2 + ((long)batch * N + gn) * 2048 + jj) = *(uint2*)o;
                    }
                } else {
                    u16* dst = (u16*)Cout + (long)bz * ((long)M * N);
#pragma unroll
                    for (int q = 0; q < 4; q++)
#pragma unroll
                        for (int d = 0; d < 4; d++)
                            dst[(long)(gb + q*8 + hi*4 + d) * N + gn] = f2bf(acc[i][j][q*4+d] + bv);
                }
            } else if (MODE == 5) {
#pragma unroll
                for (int q = 0; q < 4; q++) {
                    const int r0 = gb + q * 8 + hi * 4;
                    const float4 l4 = *(const float4*)(bias + (long)bz * 2048 + r0);
                    ((float*)Cout)[(long)bz * sC + (long)(r0+0) * N + gn] = acc[i][j][q*4+0] * (1.0f / l4.x);
                    ((float*)Cout)[(long)bz * sC + (long)(r0+1) * N + gn] = acc[i][j][q*4+1] * (1.0f / l4.y);
                    ((float*)Cout)[(long)bz * sC + (long)(r0+2) * N + gn] = acc[i][j][q*4+2] * (1.0f / l4.z);
                    ((float*)Cout)[(long)bz * sC + (long)(r0+3) * N + gn] = acc[i][j][q*4+3] * (1.0f / l4.w);
                }
            } else {  // MODE 2
#pragma unroll
                for (int q = 0; q < 4; q++)
#pragma unroll
                    for (int d = 0; d < 4; d++) {
                        const float e = __expf(acc[i][j][q*4+d] * scale);
                        const u16 h = f2bf(e);
                        ((u16*)Cout)[(long)bz * sC + (long)(gb + q*8 + hi*4 + d) * N + gn] = h;
                        rs[q*4+d] += bf2f(h);
                    }
            }
        }
        if (MODE == 2) {
            // reduce each row sum across the 32-lane (l&31) group, 1 atomic/row
#pragma unroll
            for (int r = 0; r < 16; r++) {
                float s = rs[r];
                s += __shfl_xor(s, 1);
                s += __shfl_xor(s, 2);
                s += __shfl_xor(s, 4);
                s += __shfl_xor(s, 8);
                s += __shfl_xor(s, 16);
                if (cn == 0)
                    atomicAdd((float*)Cout2 + (long)bz * 2048 + gb + (r>>2)*8 + hi*4 + (r&3), s);
            }
        }
    }
}

extern "C" void kernel_launch(void* const* d_in, const int* in_sizes, int n_in,
                              void* d_out, int out_size, void* d_ws, size_t ws_size,
                              hipStream_t stream) {
    const float* target = (const float*)d_in[0];
    const float* src_k  = (const float*)d_in[1];
    const float* src_v  = (const float*)d_in[2];
    const float* Wq = (const float*)d_in[3];
    const float* bq = (const float*)d_in[4];
    const float* Wk = (const float*)d_in[5];
    const float* bk = (const float*)d_in[6];
    const float* Wv = (const float*)d_in[7];
    const float* bv = (const float*)d_in[8];
    const float* g_t = (const float*)d_in[9];
    const float* b_t = (const float*)d_in[10];
    const float* g_k = (const float*)d_in[11];
    const float* b_k = (const float*)d_in[12];
    const float* g_v = (const float*)d_in[13];
    const float* b_v = (const float*)d_in[14];

    char* ws = (char*)d_ws;
    const float scale = 0.03125f;  // 1024^-0.5
    const size_t MB = 1048576;

    if (ws_size >= 198 * MB) {
        // merged path: peak 198 MB
        u16* q   = (u16*)(ws + 0);            // 16384x1024 bf16 (q,kk contiguous)
        u16* kk  = (u16*)(ws + 32 * MB);
        u16* vT  = (u16*)(ws + 64 * MB);      // 8 x 1024 x 2048 bf16
        u16* ln3 = (u16*)(ws + 96 * MB);      // 3 x 16384x1024 bf16 (dead after proj)
        u16* wqb = (u16*)(ws + 192 * MB);     // 3 x 1024x1024 bf16
        u16* S   = (u16*)(ws + 96 * MB);      // 8x2048x2048 bf16 = 96..160 MB
        float* L = (float*)(ws + 160 * MB);   // 8x2048 fp32 denominators (dead ln3 tail)

        cast3_kernel<<<3072, 256, 0, stream>>>(Wq, Wk, Wv, wqb);
        ln3_kernel<<<49152, 256, 0, stream>>>(target, src_k, src_v,
                                              g_t, g_k, g_v, b_t, b_k, b_v, ln3);
        // Q/K/V projections: 256^2 8-phase kernel, one dispatch (z = projection)
        gemm8<4><<<dim3(64, 4, 3), 512, 0, stream>>>(ln3, wqb, bq, bk, bv,
            q, vT, 16384, 1024, 1024, 1.0f, 16777216L, 1048576L, 0);
        // zero denominators (must be after QKV: L aliases dead ln3 space)
        zerof_kernel<<<64, 256, 0, stream>>>(L);
        // P[b] = exp((q[b] @ k[b]^T) * scale), rowsums -> L
        gemm8<2><<<512, 512, 0, stream>>>(q, kk, nullptr, nullptr, nullptr, S, L,
            2048, 2048, 1024, scale, 2048L * 1024, 2048L * 1024, 2048L * 2048);
        // out[b] = (P[b] @ vT[b]^T) / L[row]
        gemm8<5><<<256, 512, 0, stream>>>(S, vT, L, nullptr, nullptr, d_out, nullptr,
            2048, 1024, 2048, 1.0f, 2048L * 2048, 1024L * 2048, 2048L * 1024);
    } else {
        // fallback (r6) path: peak ~140.5 MB
        u16* q   = (u16*)(ws + 0);
        u16* kk  = (u16*)(ws + 32 * MB);
        u16* vT  = (u16*)(ws + 64 * MB);
        u16* ln  = (u16*)(ws + 96 * MB);
        u16* wqb = (u16*)(ws + 128 * MB);
        u16* wkb = wqb + 1048576;
        u16* wvb = wkb + 1048576;
        u16* S   = (u16*)(ws + 96 * MB);

        cast3_kernel<<<3072, 256, 0, stream>>>(Wq, Wk, Wv, wqb);
        ln_cast_kernel<<<16384, 256, 0, stream>>>(target, g_t, b_t, ln);
        gemm_bt<0><<<dim3(128, 8, 1), 256, 0, stream>>>(ln, wqb, bq, nullptr, nullptr,
            q, nullptr, 16384, 1024, 1024, 1.0f, 0, 0, 0);
        ln_cast_kernel<<<16384, 256, 0, stream>>>(src_k, g_k, b_k, ln);
        gemm_bt<0><<<dim3(128, 8, 1), 256, 0, stream>>>(ln, wkb, bk, nullptr, nullptr,
            kk, nullptr, 16384, 1024, 1024, 1.0f, 0, 0, 0);
        ln_cast_kernel<<<16384, 256, 0, stream>>>(src_v, g_v, b_v, ln);
        gemm_bt<1><<<dim3(128, 8, 1), 256, 0, stream>>>(ln, wvb, bv, nullptr, nullptr,
            vT, nullptr, 16384, 1024, 1024, 1.0f, 0, 0, 0);
        gemm_bt<2><<<2048, 256, 0, stream>>>(q, kk, nullptr, nullptr, nullptr, S, nullptr,
            2048, 2048, 1024, scale, 2048L * 1024, 2048L * 1024, 2048L * 2048);
        gemm_bt<3><<<1024, 256, 0, stream>>>(S, vT, nullptr, nullptr, nullptr, d_out, nullptr,
            2048, 1024, 2048, 1.0f, 2048L * 2048, 1024L * 2048, 2048L * 1024);
    }
}